// Round 1
// baseline (2577.014 us; speedup 1.0000x reference)
//
#include <hip/hip_runtime.h>
#include <stdint.h>
#include <math.h>

// ---------------- problem constants ----------------
#define T_TOK 2048
#define H_DIM 2880
#define I_DIM 2880
#define E_NUM 16
#define TOPK 4

// GEMM tiling
#define BT 128      // tokens per block tile
#define BW 64       // weight rows (output features) per block tile
#define BK 64       // K chunk
#define MT_MAX 16   // max token tiles per expert (2048/128)
#define NTILES 45   // 2880/64

typedef __bf16 bf16_t;
typedef __bf16 bf16x8 __attribute__((ext_vector_type(8)));
typedef __bf16 bf16x4 __attribute__((ext_vector_type(4)));
typedef float f32x4 __attribute__((ext_vector_type(4)));

__device__ __forceinline__ void gload16(const bf16_t* g, bf16_t* l) {
  __builtin_amdgcn_global_load_lds(
      (__attribute__((address_space(1))) const uint32_t*)g,
      (__attribute__((address_space(3))) uint32_t*)l, 16, 0, 0);
}

__device__ __forceinline__ f32x4 mfma16(bf16x8 a, bf16x8 b, f32x4 c) {
  return __builtin_amdgcn_mfma_f32_16x16x32_bf16(a, b, c, 0, 0, 0);
}

// ---------------- prep: x -> bf16, zero counts ----------------
__global__ void k_prep(const float* __restrict__ x, bf16_t* __restrict__ xbf,
                       int* __restrict__ counts) {
  if (blockIdx.x == 0 && threadIdx.x < E_NUM) counts[threadIdx.x] = 0;
  int idx = blockIdx.x * 256 + threadIdx.x;
  const int total = T_TOK * H_DIM / 8;
  if (idx < total) {
    f32x4 a = ((const f32x4*)x)[2 * idx];
    f32x4 b = ((const f32x4*)x)[2 * idx + 1];
    bf16x8 o = {(bf16_t)a[0], (bf16_t)a[1], (bf16_t)a[2], (bf16_t)a[3],
                (bf16_t)b[0], (bf16_t)b[1], (bf16_t)b[2], (bf16_t)b[3]};
    ((bf16x8*)xbf)[idx] = o;
  }
}

// ---------------- router: fp32 logits, top-4, softmax, expert lists --------
__global__ void k_router(const float* __restrict__ x, const float* __restrict__ gw,
                         const float* __restrict__ gb, float* __restrict__ topw,
                         int* __restrict__ counts, int* __restrict__ rowsl) {
  const int t = blockIdx.x;
  const int lane = threadIdx.x;      // 64 threads
  const int c = lane >> 4, e = lane & 15;
  const f32x4* x4 = (const f32x4*)(x + (size_t)t * H_DIM);
  const f32x4* w4 = (const f32x4*)(gw + (size_t)e * H_DIM);
  float p = 0.f;
  const int per = (H_DIM / 4) / 4;   // 180 float4 per c-segment
  for (int i = c * per; i < (c + 1) * per; ++i) {
    f32x4 xv = x4[i], wv = w4[i];
    p += xv[0] * wv[0] + xv[1] * wv[1] + xv[2] * wv[2] + xv[3] * wv[3];
  }
  p += __shfl_xor(p, 16);
  p += __shfl_xor(p, 32);
  p += gb[e];
  __shared__ float lg[E_NUM];
  if (lane < E_NUM) lg[lane] = p;
  __syncthreads();
  if (lane == 0) {
    float v[E_NUM];
    #pragma unroll
    for (int i = 0; i < E_NUM; ++i) v[i] = lg[i];
    int idxs[TOPK]; float vals[TOPK];
    for (int k = 0; k < TOPK; ++k) {
      int bi = 0; float bv = -1e30f;
      for (int i = 0; i < E_NUM; ++i) {
        if (v[i] > bv) { bv = v[i]; bi = i; }
      }
      idxs[k] = bi; vals[k] = bv; v[bi] = -1e30f;
    }
    float m = vals[0], s = 0.f, w[TOPK];
    for (int k = 0; k < TOPK; ++k) { w[k] = expf(vals[k] - m); s += w[k]; }
    for (int k = 0; k < TOPK; ++k) {
      int slot = t * TOPK + k;
      topw[slot] = w[k] / s;
      int pos = atomicAdd(&counts[idxs[k]], 1);
      rowsl[idxs[k] * T_TOK + pos] = slot;
    }
  }
}

// ---------------- GEMM1: h = x @ wgu^T (+bias), swiglu -> act (bf16) -------
__global__ __launch_bounds__(256, 2)
void k_gemm1(const bf16_t* __restrict__ xbf, const float* __restrict__ wgu,
             const float* __restrict__ bgu, const float* __restrict__ al,
             const float* __restrict__ be, const float* __restrict__ lim_,
             const int* __restrict__ counts, const int* __restrict__ rowsl,
             bf16_t* __restrict__ act) {
  const int bid = blockIdx.x;
  const int mt = bid & (MT_MAX - 1);
  const int t2 = bid >> 4;
  const int nt = t2 % NTILES;
  const int e = t2 / NTILES;
  const int Ne = counts[e];
  const int m0 = mt * BT;
  if (m0 >= Ne) return;
  const int n0 = nt * BW;

  __shared__ alignas(16) bf16_t sWg[BW * BK];
  __shared__ alignas(16) bf16_t sWl[BW * BK];
  __shared__ alignas(16) bf16_t sTk[BT * BK];

  const int tid = threadIdx.x;
  const int w = tid >> 6, lane = tid & 63;
  const int wm = w & 1, wt = w >> 1;
  const int* rl = rowsl + e * T_TOK;

  // per-lane pre-swizzled global sources for token staging
  const bf16_t* tsrc[4];
  {
    const int r_ = lane >> 3, cc = lane & 7;
    #pragma unroll
    for (int i = 0; i < 4; ++i) {
      int r = w * 32 + i * 8 + r_;
      int li = m0 + r; if (li > Ne - 1) li = Ne - 1;
      int tok = rl[li] >> 2;
      tsrc[i] = xbf + (size_t)tok * H_DIM + ((cc ^ (r & 7)) << 3);
    }
  }

  // weight staging coords: 16 lanes x 16 float4 cover a row; 4 reps of 16 rows
  const int wrow = tid >> 4;   // 0..15
  const int wf = tid & 15;     // float4 index in row
  const float* wg0 = wgu + ((size_t)e * (2 * I_DIM) + (n0 + wrow)) * H_DIM;
  const float* wl0 = wg0 + (size_t)I_DIM * H_DIM;

  f32x4 zero = {0.f, 0.f, 0.f, 0.f};
  f32x4 accg[2][4], accl[2][4];
  #pragma unroll
  for (int i = 0; i < 2; ++i)
    #pragma unroll
    for (int j = 0; j < 4; ++j) { accg[i][j] = zero; accl[i][j] = zero; }

  for (int kk = 0; kk < H_DIM / BK; ++kk) {
    const int k0 = kk * BK;
    #pragma unroll
    for (int i = 0; i < 4; ++i)
      gload16(tsrc[i] + k0, &sTk[w * 2048 + i * 512]);
    #pragma unroll
    for (int rep = 0; rep < 4; ++rep) {
      int row = wrow + rep * 16;
      f32x4 vg = *(const f32x4*)(wg0 + (size_t)rep * 16 * H_DIM + k0 + wf * 4);
      f32x4 vl = *(const f32x4*)(wl0 + (size_t)rep * 16 * H_DIM + k0 + wf * 4);
      bf16x4 bg4 = {(bf16_t)vg[0], (bf16_t)vg[1], (bf16_t)vg[2], (bf16_t)vg[3]};
      bf16x4 bl4 = {(bf16_t)vl[0], (bf16_t)vl[1], (bf16_t)vl[2], (bf16_t)vl[3]};
      int off = row * 64 + ((wf * 4) ^ ((row & 7) << 3));
      *(bf16x4*)(&sWg[off]) = bg4;
      *(bf16x4*)(&sWl[off]) = bl4;
    }
    __syncthreads();
    #pragma unroll
    for (int ks = 0; ks < 2; ++ks) {
      const int koff = ks * 32 + (lane >> 4) * 8;
      bf16x8 wg_[2], wl_[2], tf[4];
      #pragma unroll
      for (int wi = 0; wi < 2; ++wi) {
        int row = 32 * wm + 16 * wi + (lane & 15);
        int off = row * 64 + (koff ^ ((row & 7) << 3));
        wg_[wi] = *(const bf16x8*)(&sWg[off]);
        wl_[wi] = *(const bf16x8*)(&sWl[off]);
      }
      #pragma unroll
      for (int tj = 0; tj < 4; ++tj) {
        int row = 64 * wt + 16 * tj + (lane & 15);
        int off = row * 64 + (koff ^ ((row & 7) << 3));
        tf[tj] = *(const bf16x8*)(&sTk[off]);
      }
      #pragma unroll
      for (int wi = 0; wi < 2; ++wi)
        #pragma unroll
        for (int tj = 0; tj < 4; ++tj) {
          accg[wi][tj] = mfma16(wg_[wi], tf[tj], accg[wi][tj]);
          accl[wi][tj] = mfma16(wl_[wi], tf[tj], accl[wi][tj]);
        }
    }
    __syncthreads();
  }

  const float alpha = al[e], beta = be[e], lim = lim_[e];
  const float* bgp = bgu + (size_t)e * (2 * I_DIM);
  #pragma unroll
  for (int wi = 0; wi < 2; ++wi) {
    const int nb = n0 + 32 * wm + 16 * wi + ((lane >> 4) << 2);
    f32x4 bg4 = *(const f32x4*)(bgp + nb);
    f32x4 bl4 = *(const f32x4*)(bgp + I_DIM + nb);
    #pragma unroll
    for (int tj = 0; tj < 4; ++tj) {
      const int li2 = m0 + 64 * wt + 16 * tj + (lane & 15);
      if (li2 < Ne) {
        const int slot = rl[li2];
        bf16x4 ov;
        #pragma unroll
        for (int r = 0; r < 4; ++r) {
          float g = accg[wi][tj][r] + bg4[r];
          float l = accl[wi][tj][r] + bl4[r];
          g = fminf(g, lim);
          l = fminf(fmaxf(l, -lim), lim);
          float sg = 1.0f / (1.0f + expf(-alpha * g));
          ov[r] = (bf16_t)(g * sg * (l + beta));
        }
        *(bf16x4*)(&act[(size_t)slot * I_DIM + nb]) = ov;
      }
    }
  }
}

// ---------------- GEMM2: y = act @ wd^T + bd, scaled by routing weight -----
__global__ __launch_bounds__(256, 2)
void k_gemm2(const bf16_t* __restrict__ act, const float* __restrict__ wd,
             const float* __restrict__ bd, const float* __restrict__ topw,
             const int* __restrict__ counts, const int* __restrict__ rowsl,
             float* __restrict__ ybuf) {
  const int bid = blockIdx.x;
  const int mt = bid & (MT_MAX - 1);
  const int t2 = bid >> 4;
  const int ht = t2 % NTILES;
  const int e = t2 / NTILES;
  const int Ne = counts[e];
  const int m0 = mt * BT;
  if (m0 >= Ne) return;
  const int h0 = ht * BW;

  __shared__ alignas(16) bf16_t sWd[BW * BK];
  __shared__ alignas(16) bf16_t sTk[BT * BK];

  const int tid = threadIdx.x;
  const int w = tid >> 6, lane = tid & 63;
  const int wm = w & 1, wt = w >> 1;
  const int* rl = rowsl + e * T_TOK;

  const bf16_t* tsrc[4];
  {
    const int r_ = lane >> 3, cc = lane & 7;
    #pragma unroll
    for (int i = 0; i < 4; ++i) {
      int r = w * 32 + i * 8 + r_;
      int li = m0 + r; if (li > Ne - 1) li = Ne - 1;
      int slot = rl[li];
      tsrc[i] = act + (size_t)slot * I_DIM + ((cc ^ (r & 7)) << 3);
    }
  }

  const int wrow = tid >> 4;
  const int wf = tid & 15;
  const float* wd0 = wd + ((size_t)e * H_DIM + (h0 + wrow)) * I_DIM;

  f32x4 zero = {0.f, 0.f, 0.f, 0.f};
  f32x4 acc[2][4];
  #pragma unroll
  for (int i = 0; i < 2; ++i)
    #pragma unroll
    for (int j = 0; j < 4; ++j) acc[i][j] = zero;

  for (int kk = 0; kk < I_DIM / BK; ++kk) {
    const int k0 = kk * BK;
    #pragma unroll
    for (int i = 0; i < 4; ++i)
      gload16(tsrc[i] + k0, &sTk[w * 2048 + i * 512]);
    #pragma unroll
    for (int rep = 0; rep < 4; ++rep) {
      int row = wrow + rep * 16;
      f32x4 vw = *(const f32x4*)(wd0 + (size_t)rep * 16 * I_DIM + k0 + wf * 4);
      bf16x4 b4 = {(bf16_t)vw[0], (bf16_t)vw[1], (bf16_t)vw[2], (bf16_t)vw[3]};
      int off = row * 64 + ((wf * 4) ^ ((row & 7) << 3));
      *(bf16x4*)(&sWd[off]) = b4;
    }
    __syncthreads();
    #pragma unroll
    for (int ks = 0; ks < 2; ++ks) {
      const int koff = ks * 32 + (lane >> 4) * 8;
      bf16x8 wf_[2], tf[4];
      #pragma unroll
      for (int wi = 0; wi < 2; ++wi) {
        int row = 32 * wm + 16 * wi + (lane & 15);
        int off = row * 64 + (koff ^ ((row & 7) << 3));
        wf_[wi] = *(const bf16x8*)(&sWd[off]);
      }
      #pragma unroll
      for (int tj = 0; tj < 4; ++tj) {
        int row = 64 * wt + 16 * tj + (lane & 15);
        int off = row * 64 + (koff ^ ((row & 7) << 3));
        tf[tj] = *(const bf16x8*)(&sTk[off]);
      }
      #pragma unroll
      for (int wi = 0; wi < 2; ++wi)
        #pragma unroll
        for (int tj = 0; tj < 4; ++tj)
          acc[wi][tj] = mfma16(wf_[wi], tf[tj], acc[wi][tj]);
    }
    __syncthreads();
  }

  const float* bdp = bd + (size_t)e * H_DIM;
  #pragma unroll
  for (int wi = 0; wi < 2; ++wi) {
    const int hb = h0 + 32 * wm + 16 * wi + ((lane >> 4) << 2);
    f32x4 b4 = *(const f32x4*)(bdp + hb);
    #pragma unroll
    for (int tj = 0; tj < 4; ++tj) {
      const int li2 = m0 + 64 * wt + 16 * tj + (lane & 15);
      if (li2 < Ne) {
        const int slot = rl[li2];
        const float tw = topw[slot];
        f32x4 o = (acc[wi][tj] + b4) * tw;
        *(f32x4*)(&ybuf[(size_t)slot * H_DIM + hb]) = o;
      }
    }
  }
}

// ---------------- combine: out[t] = sum_k ybuf[4t+k] ----------------------
__global__ void k_combine(const float* __restrict__ ybuf, float* __restrict__ out) {
  const int j4 = H_DIM / 4;  // 720
  int idx = blockIdx.x * 256 + threadIdx.x;
  if (idx >= T_TOK * j4) return;
  int t = idx / j4, j = idx - t * j4;
  const f32x4* yb = (const f32x4*)ybuf;
  f32x4 s = yb[(size_t)(t * 4 + 0) * j4 + j];
  s = s + yb[(size_t)(t * 4 + 1) * j4 + j];
  s = s + yb[(size_t)(t * 4 + 2) * j4 + j];
  s = s + yb[(size_t)(t * 4 + 3) * j4 + j];
  ((f32x4*)out)[idx] = s;
}

// ---------------- host launcher ----------------
extern "C" void kernel_launch(void* const* d_in, const int* in_sizes, int n_in,
                              void* d_out, int out_size, void* d_ws, size_t ws_size,
                              hipStream_t stream) {
  const float* x   = (const float*)d_in[0];
  const float* gw  = (const float*)d_in[1];
  const float* gb  = (const float*)d_in[2];
  const float* wgu = (const float*)d_in[3];
  const float* bgu = (const float*)d_in[4];
  const float* wd  = (const float*)d_in[5];
  const float* bd  = (const float*)d_in[6];
  const float* sal = (const float*)d_in[7];
  const float* sbe = (const float*)d_in[8];
  const float* sli = (const float*)d_in[9];
  float* out = (float*)d_out;

  char* ws = (char*)d_ws;
  int*    counts = (int*)(ws + 0);
  int*    rowsl  = (int*)(ws + 4096);
  float*  topw   = (float*)(ws + 4096 + 131072);
  bf16_t* xbf    = (bf16_t*)(ws + (1 << 20));
  bf16_t* act    = (bf16_t*)(ws + (size_t)(16 << 20));
  float*  ybuf   = (float*)(ws + (size_t)(64 << 20));

  k_prep<<<dim3(2880), dim3(256), 0, stream>>>(x, xbf, counts);
  k_router<<<dim3(T_TOK), dim3(64), 0, stream>>>(x, gw, gb, topw, counts, rowsl);
  k_gemm1<<<dim3(E_NUM * NTILES * MT_MAX), dim3(256), 0, stream>>>(
      xbf, wgu, bgu, sal, sbe, sli, counts, rowsl, act);
  k_gemm2<<<dim3(E_NUM * NTILES * MT_MAX), dim3(256), 0, stream>>>(
      act, wd, bd, topw, counts, rowsl, ybuf);
  k_combine<<<dim3(5760), dim3(256), 0, stream>>>(ybuf, out);
}

// Round 2
// 1716.297 us; speedup vs baseline: 1.5015x; 1.5015x over previous
//
#include <hip/hip_runtime.h>
#include <stdint.h>
#include <math.h>

// ---------------- problem constants ----------------
#define T_TOK 2048
#define H_DIM 2880
#define I_DIM 2880
#define E_NUM 16
#define TOPK 4

#define BT 128      // tokens per block tile
#define BK 64       // K chunk
#define MT_MAX 16   // max token tiles per expert (2048/128)
#define NT1 45      // 2880/64 output tiles (gemm1: 64 gate + 64 lin rows)
#define NT2 45      // 2880/64 output tiles (gemm2)

typedef __bf16 bf16_t;
typedef __bf16 bf16x8 __attribute__((ext_vector_type(8)));
typedef __bf16 bf16x4 __attribute__((ext_vector_type(4)));
typedef float f32x4 __attribute__((ext_vector_type(4)));

__device__ __forceinline__ void gload16(const bf16_t* g, bf16_t* l) {
  __builtin_amdgcn_global_load_lds(
      (__attribute__((address_space(1))) const uint32_t*)g,
      (__attribute__((address_space(3))) uint32_t*)l, 16, 0, 0);
}

__device__ __forceinline__ f32x4 mfma16(bf16x8 a, bf16x8 b, f32x4 c) {
  return __builtin_amdgcn_mfma_f32_16x16x32_bf16(a, b, c, 0, 0, 0);
}

// ---------------- prep: x -> bf16, zero counts ----------------
__global__ void k_prep(const float* __restrict__ x, bf16_t* __restrict__ xbf,
                       int* __restrict__ counts) {
  if (blockIdx.x == 0 && threadIdx.x < E_NUM) counts[threadIdx.x] = 0;
  int idx = blockIdx.x * 256 + threadIdx.x;
  const int total = T_TOK * H_DIM / 8;
  if (idx < total) {
    f32x4 a = ((const f32x4*)x)[2 * idx];
    f32x4 b = ((const f32x4*)x)[2 * idx + 1];
    bf16x8 o = {(bf16_t)a[0], (bf16_t)a[1], (bf16_t)a[2], (bf16_t)a[3],
                (bf16_t)b[0], (bf16_t)b[1], (bf16_t)b[2], (bf16_t)b[3]};
    ((bf16x8*)xbf)[idx] = o;
  }
}

// ---------------- router ----------------
__global__ void k_router(const float* __restrict__ x, const float* __restrict__ gw,
                         const float* __restrict__ gb, float* __restrict__ topw,
                         int* __restrict__ counts, int* __restrict__ rowsl) {
  const int t = blockIdx.x;
  const int lane = threadIdx.x;      // 64 threads
  const int c = lane >> 4, e = lane & 15;
  const f32x4* x4 = (const f32x4*)(x + (size_t)t * H_DIM);
  const f32x4* w4 = (const f32x4*)(gw + (size_t)e * H_DIM);
  float p = 0.f;
  const int per = (H_DIM / 4) / 4;
  for (int i = c * per; i < (c + 1) * per; ++i) {
    f32x4 xv = x4[i], wv = w4[i];
    p += xv[0] * wv[0] + xv[1] * wv[1] + xv[2] * wv[2] + xv[3] * wv[3];
  }
  p += __shfl_xor(p, 16);
  p += __shfl_xor(p, 32);
  p += gb[e];
  __shared__ float lg[E_NUM];
  if (lane < E_NUM) lg[lane] = p;
  __syncthreads();
  if (lane == 0) {
    float v[E_NUM];
    #pragma unroll
    for (int i = 0; i < E_NUM; ++i) v[i] = lg[i];
    int idxs[TOPK]; float vals[TOPK];
    for (int k = 0; k < TOPK; ++k) {
      int bi = 0; float bv = -1e30f;
      for (int i = 0; i < E_NUM; ++i) {
        if (v[i] > bv) { bv = v[i]; bi = i; }
      }
      idxs[k] = bi; vals[k] = bv; v[bi] = -1e30f;
    }
    float m = vals[0], s = 0.f, w[TOPK];
    for (int k = 0; k < TOPK; ++k) { w[k] = expf(vals[k] - m); s += w[k]; }
    for (int k = 0; k < TOPK; ++k) {
      int slot = t * TOPK + k;
      topw[slot] = w[k] / s;
      int pos = atomicAdd(&counts[idxs[k]], 1);
      rowsl[idxs[k] * T_TOK + pos] = slot;
    }
  }
}

// ---------------- GEMM1: h = x @ wgu^T (+bias), swiglu -> act (bf16) -------
// 2-phase pipeline: dbuf LDS, token gload_lds + fp32-weight reg-prefetch (T14)
__global__ __launch_bounds__(256, 2)
void k_gemm1(const bf16_t* __restrict__ xbf, const float* __restrict__ wgu,
             const float* __restrict__ bgu, const float* __restrict__ al,
             const float* __restrict__ be, const float* __restrict__ lim_,
             const int* __restrict__ counts, const int* __restrict__ rowsl,
             bf16_t* __restrict__ act) {
  // XCD-bijective swizzle (nwg % 8 == 0): same-weight (mt-adjacent) blocks -> same XCD
  const int nwg = E_NUM * NT1 * MT_MAX;
  const int L = (blockIdx.x & 7) * (nwg >> 3) + (blockIdx.x >> 3);
  const int mt = L & (MT_MAX - 1);
  const int t2 = L >> 4;
  const int nt = t2 % NT1;
  const int e  = t2 / NT1;
  const int Ne = counts[e];
  const int m0 = mt * BT;
  if (m0 >= Ne) return;
  const int n0 = nt * 64;

  __shared__ alignas(16) bf16_t sW[2][128 * 64];  // rows 0-63 gate, 64-127 lin
  __shared__ alignas(16) bf16_t sT[2][128 * 64];

  const int tid = threadIdx.x;
  const int w = tid >> 6, lane = tid & 63;
  const int wm = w & 1, wt = w >> 1;
  const int* rl = rowsl + e * T_TOK;

  // token staging sources (pre-swizzled global addr, linear LDS dest)
  const bf16_t* tsrc[4];
  {
    const int r_ = lane >> 3, cc = lane & 7;
    #pragma unroll
    for (int i = 0; i < 4; ++i) {
      int r = w * 32 + i * 8 + r_;
      int li = m0 + r; if (li > Ne - 1) li = Ne - 1;
      int tok = rl[li] >> 2;
      tsrc[i] = xbf + (size_t)tok * H_DIM + ((cc ^ (r & 7)) << 3);
    }
  }

  // weight staging: 16 threads/row, 8 rows-of-16 passes -> 128 rows x 64 cols
  const int wrow = tid >> 4, wf = tid & 15;
  const float* wbase = wgu + (size_t)e * (2 * I_DIM) * H_DIM + wf * 4;
  int wgo[8], wo[8];
  #pragma unroll
  for (int p = 0; p < 8; ++p) {
    int row = wrow + p * 16;   // 0..127
    int grow = (row < 64) ? (n0 + row) : (I_DIM + n0 + row - 64);
    wgo[p] = grow * H_DIM;
    wo[p] = row * 64 + ((wf * 4) ^ ((row & 7) << 3));
  }

  f32x4 zero = {0.f, 0.f, 0.f, 0.f};
  f32x4 accg[2][4], accl[2][4];
  #pragma unroll
  for (int i = 0; i < 2; ++i)
    #pragma unroll
    for (int j = 0; j < 4; ++j) { accg[i][j] = zero; accl[i][j] = zero; }

  f32x4 wreg[8];
  // prologue: stage tile 0 into buf 0
  #pragma unroll
  for (int i = 0; i < 4; ++i) gload16(tsrc[i], &sT[0][w * 2048 + i * 512]);
  #pragma unroll
  for (int p = 0; p < 8; ++p) wreg[p] = *(const f32x4*)(wbase + wgo[p]);
  #pragma unroll
  for (int p = 0; p < 8; ++p) {
    bf16x4 b = {(bf16_t)wreg[p][0], (bf16_t)wreg[p][1],
                (bf16_t)wreg[p][2], (bf16_t)wreg[p][3]};
    *(bf16x4*)(&sW[0][wo[p]]) = b;
  }
  __syncthreads();

  for (int kk = 0; kk < H_DIM / BK; ++kk) {
    const int cur = kk & 1;
    const int knxt = (kk + 1) * BK;
    const bool has_next = (kk < H_DIM / BK - 1);
    if (has_next) {
      #pragma unroll
      for (int i = 0; i < 4; ++i)
        gload16(tsrc[i] + knxt, &sT[cur ^ 1][w * 2048 + i * 512]);
      #pragma unroll
      for (int p = 0; p < 8; ++p)
        wreg[p] = *(const f32x4*)(wbase + (wgo[p] + knxt));
    }
    #pragma unroll
    for (int ks = 0; ks < 2; ++ks) {
      const int koff = ks * 32 + (lane >> 4) * 8;
      bf16x8 wg_[2], wl_[2], tf[4];
      #pragma unroll
      for (int wi = 0; wi < 2; ++wi) {
        int rg = 32 * wm + 16 * wi + (lane & 15);
        int swz = koff ^ ((rg & 7) << 3);   // (rg+64)&7 == rg&7
        wg_[wi] = *(const bf16x8*)(&sW[cur][rg * 64 + swz]);
        wl_[wi] = *(const bf16x8*)(&sW[cur][(rg + 64) * 64 + swz]);
      }
      #pragma unroll
      for (int tj = 0; tj < 4; ++tj) {
        int rt = 64 * wt + 16 * tj + (lane & 15);
        tf[tj] = *(const bf16x8*)(&sT[cur][rt * 64 + (koff ^ ((rt & 7) << 3))]);
      }
      #pragma unroll
      for (int wi = 0; wi < 2; ++wi)
        #pragma unroll
        for (int tj = 0; tj < 4; ++tj) {
          accg[wi][tj] = mfma16(wg_[wi], tf[tj], accg[wi][tj]);
          accl[wi][tj] = mfma16(wl_[wi], tf[tj], accl[wi][tj]);
        }
    }
    if (has_next) {
      #pragma unroll
      for (int p = 0; p < 8; ++p) {
        bf16x4 b = {(bf16_t)wreg[p][0], (bf16_t)wreg[p][1],
                    (bf16_t)wreg[p][2], (bf16_t)wreg[p][3]};
        *(bf16x4*)(&sW[cur ^ 1][wo[p]]) = b;
      }
    }
    __syncthreads();
  }

  const float alpha = al[e], beta = be[e], lim = lim_[e];
  const float* bgp = bgu + (size_t)e * (2 * I_DIM);
  #pragma unroll
  for (int wi = 0; wi < 2; ++wi) {
    const int nb = n0 + 32 * wm + 16 * wi + ((lane >> 4) << 2);
    f32x4 bg4 = *(const f32x4*)(bgp + nb);
    f32x4 bl4 = *(const f32x4*)(bgp + I_DIM + nb);
    #pragma unroll
    for (int tj = 0; tj < 4; ++tj) {
      const int li2 = m0 + 64 * wt + 16 * tj + (lane & 15);
      if (li2 < Ne) {
        const int slot = rl[li2];
        bf16x4 ov;
        #pragma unroll
        for (int r = 0; r < 4; ++r) {
          float g = accg[wi][tj][r] + bg4[r];
          float l = accl[wi][tj][r] + bl4[r];
          g = fminf(g, lim);
          l = fminf(fmaxf(l, -lim), lim);
          float sg = 1.0f / (1.0f + expf(-alpha * g));
          ov[r] = (bf16_t)(g * sg * (l + beta));
        }
        *(bf16x4*)(&act[(size_t)slot * I_DIM + nb]) = ov;
      }
    }
  }
}

// ---------------- GEMM2: y = act @ wd^T + bd, scaled ----------------------
__global__ __launch_bounds__(256, 3)
void k_gemm2(const bf16_t* __restrict__ act, const float* __restrict__ wd,
             const float* __restrict__ bd, const float* __restrict__ topw,
             const int* __restrict__ counts, const int* __restrict__ rowsl,
             float* __restrict__ ybuf) {
  const int nwg = E_NUM * NT2 * MT_MAX;
  const int L = (blockIdx.x & 7) * (nwg >> 3) + (blockIdx.x >> 3);
  const int mt = L & (MT_MAX - 1);
  const int t2 = L >> 4;
  const int ht = t2 % NT2;
  const int e  = t2 / NT2;
  const int Ne = counts[e];
  const int m0 = mt * BT;
  if (m0 >= Ne) return;
  const int h0 = ht * 64;

  __shared__ alignas(16) bf16_t sW[2][64 * 64];
  __shared__ alignas(16) bf16_t sT[2][128 * 64];

  const int tid = threadIdx.x;
  const int w = tid >> 6, lane = tid & 63;
  const int wm = w & 1, wt = w >> 1;
  const int* rl = rowsl + e * T_TOK;

  const bf16_t* tsrc[4];
  {
    const int r_ = lane >> 3, cc = lane & 7;
    #pragma unroll
    for (int i = 0; i < 4; ++i) {
      int r = w * 32 + i * 8 + r_;
      int li = m0 + r; if (li > Ne - 1) li = Ne - 1;
      int slot = rl[li];
      tsrc[i] = act + (size_t)slot * I_DIM + ((cc ^ (r & 7)) << 3);
    }
  }

  const int wrow = tid >> 4, wf = tid & 15;
  const float* wbase = wd + (size_t)e * H_DIM * I_DIM + wf * 4;
  int wgo[4], wo[4];
  #pragma unroll
  for (int p = 0; p < 4; ++p) {
    int row = wrow + p * 16;   // 0..63
    wgo[p] = (h0 + row) * I_DIM;
    wo[p] = row * 64 + ((wf * 4) ^ ((row & 7) << 3));
  }

  f32x4 zero = {0.f, 0.f, 0.f, 0.f};
  f32x4 acc[2][4];
  #pragma unroll
  for (int i = 0; i < 2; ++i)
    #pragma unroll
    for (int j = 0; j < 4; ++j) acc[i][j] = zero;

  f32x4 wreg[4];
  #pragma unroll
  for (int i = 0; i < 4; ++i) gload16(tsrc[i], &sT[0][w * 2048 + i * 512]);
  #pragma unroll
  for (int p = 0; p < 4; ++p) wreg[p] = *(const f32x4*)(wbase + wgo[p]);
  #pragma unroll
  for (int p = 0; p < 4; ++p) {
    bf16x4 b = {(bf16_t)wreg[p][0], (bf16_t)wreg[p][1],
                (bf16_t)wreg[p][2], (bf16_t)wreg[p][3]};
    *(bf16x4*)(&sW[0][wo[p]]) = b;
  }
  __syncthreads();

  for (int kk = 0; kk < I_DIM / BK; ++kk) {
    const int cur = kk & 1;
    const int knxt = (kk + 1) * BK;
    const bool has_next = (kk < I_DIM / BK - 1);
    if (has_next) {
      #pragma unroll
      for (int i = 0; i < 4; ++i)
        gload16(tsrc[i] + knxt, &sT[cur ^ 1][w * 2048 + i * 512]);
      #pragma unroll
      for (int p = 0; p < 4; ++p)
        wreg[p] = *(const f32x4*)(wbase + (wgo[p] + knxt));
    }
    #pragma unroll
    for (int ks = 0; ks < 2; ++ks) {
      const int koff = ks * 32 + (lane >> 4) * 8;
      bf16x8 wf_[2], tf[4];
      #pragma unroll
      for (int wi = 0; wi < 2; ++wi) {
        int rg = 32 * wm + 16 * wi + (lane & 15);
        wf_[wi] = *(const bf16x8*)(&sW[cur][rg * 64 + (koff ^ ((rg & 7) << 3))]);
      }
      #pragma unroll
      for (int tj = 0; tj < 4; ++tj) {
        int rt = 64 * wt + 16 * tj + (lane & 15);
        tf[tj] = *(const bf16x8*)(&sT[cur][rt * 64 + (koff ^ ((rt & 7) << 3))]);
      }
      #pragma unroll
      for (int wi = 0; wi < 2; ++wi)
        #pragma unroll
        for (int tj = 0; tj < 4; ++tj)
          acc[wi][tj] = mfma16(wf_[wi], tf[tj], acc[wi][tj]);
    }
    if (has_next) {
      #pragma unroll
      for (int p = 0; p < 4; ++p) {
        bf16x4 b = {(bf16_t)wreg[p][0], (bf16_t)wreg[p][1],
                    (bf16_t)wreg[p][2], (bf16_t)wreg[p][3]};
        *(bf16x4*)(&sW[cur ^ 1][wo[p]]) = b;
      }
    }
    __syncthreads();
  }

  const float* bdp = bd + (size_t)e * H_DIM;
  #pragma unroll
  for (int wi = 0; wi < 2; ++wi) {
    const int hb = h0 + 32 * wm + 16 * wi + ((lane >> 4) << 2);
    f32x4 b4 = *(const f32x4*)(bdp + hb);
    #pragma unroll
    for (int tj = 0; tj < 4; ++tj) {
      const int li2 = m0 + 64 * wt + 16 * tj + (lane & 15);
      if (li2 < Ne) {
        const int slot = rl[li2];
        const float tw = topw[slot];
        f32x4 o = (acc[wi][tj] + b4) * tw;
        *(f32x4*)(&ybuf[(size_t)slot * H_DIM + hb]) = o;
      }
    }
  }
}

// ---------------- combine ----------------------
__global__ void k_combine(const float* __restrict__ ybuf, float* __restrict__ out) {
  const int j4 = H_DIM / 4;
  int idx = blockIdx.x * 256 + threadIdx.x;
  if (idx >= T_TOK * j4) return;
  int t = idx / j4, j = idx - t * j4;
  const f32x4* yb = (const f32x4*)ybuf;
  f32x4 s = yb[(size_t)(t * 4 + 0) * j4 + j];
  s = s + yb[(size_t)(t * 4 + 1) * j4 + j];
  s = s + yb[(size_t)(t * 4 + 2) * j4 + j];
  s = s + yb[(size_t)(t * 4 + 3) * j4 + j];
  ((f32x4*)out)[idx] = s;
}

// ---------------- host launcher ----------------
extern "C" void kernel_launch(void* const* d_in, const int* in_sizes, int n_in,
                              void* d_out, int out_size, void* d_ws, size_t ws_size,
                              hipStream_t stream) {
  const float* x   = (const float*)d_in[0];
  const float* gw  = (const float*)d_in[1];
  const float* gb  = (const float*)d_in[2];
  const float* wgu = (const float*)d_in[3];
  const float* bgu = (const float*)d_in[4];
  const float* wd  = (const float*)d_in[5];
  const float* bd  = (const float*)d_in[6];
  const float* sal = (const float*)d_in[7];
  const float* sbe = (const float*)d_in[8];
  const float* sli = (const float*)d_in[9];
  float* out = (float*)d_out;

  char* ws = (char*)d_ws;
  int*    counts = (int*)(ws + 0);
  int*    rowsl  = (int*)(ws + 4096);
  float*  topw   = (float*)(ws + 4096 + 131072);
  bf16_t* xbf    = (bf16_t*)(ws + (1 << 20));
  bf16_t* act    = (bf16_t*)(ws + (size_t)(16 << 20));
  float*  ybuf   = (float*)(ws + (size_t)(64 << 20));

  k_prep<<<dim3(2880), dim3(256), 0, stream>>>(x, xbf, counts);
  k_router<<<dim3(T_TOK), dim3(64), 0, stream>>>(x, gw, gb, topw, counts, rowsl);
  k_gemm1<<<dim3(E_NUM * NT1 * MT_MAX), dim3(256), 0, stream>>>(
      xbf, wgu, bgu, sal, sbe, sli, counts, rowsl, act);
  k_gemm2<<<dim3(E_NUM * NT2 * MT_MAX), dim3(256), 0, stream>>>(
      act, wd, bd, topw, counts, rowsl, ybuf);
  k_combine<<<dim3(5760), dim3(256), 0, stream>>>(ybuf, out);
}

// Round 3
// 1359.596 us; speedup vs baseline: 1.8954x; 1.2624x over previous
//
#include <hip/hip_runtime.h>
#include <stdint.h>
#include <math.h>

// ---------------- problem constants ----------------
#define T_TOK 2048
#define H_DIM 2880
#define I_DIM 2880
#define E_NUM 16
#define TOPK 4

#define BT 128      // tokens per block tile
#define BK 64       // K chunk
#define NK 45       // K tiles (2880/64)
#define MT_MAX 16   // max token tiles per expert (2048/128)
#define NT1 45      // output tiles gemm1 (64 gate + 64 lin rows each)
#define NT2 45      // output tiles gemm2

typedef __bf16 bf16_t;
typedef __bf16 bf16x8 __attribute__((ext_vector_type(8)));
typedef __bf16 bf16x4 __attribute__((ext_vector_type(4)));
typedef float f32x4 __attribute__((ext_vector_type(4)));

#define WAITV(N) asm volatile("s_waitcnt vmcnt(" #N ")" ::: "memory")
#define WAITL()  asm volatile("s_waitcnt lgkmcnt(0)" ::: "memory")
#define BAR()    asm volatile("s_barrier" ::: "memory")

__device__ __forceinline__ void gload16(const bf16_t* g, bf16_t* l) {
  __builtin_amdgcn_global_load_lds(
      (__attribute__((address_space(1))) const uint32_t*)g,
      (__attribute__((address_space(3))) uint32_t*)l, 16, 0, 0);
}

__device__ __forceinline__ f32x4 mfma16(bf16x8 a, bf16x8 b, f32x4 c) {
  return __builtin_amdgcn_mfma_f32_16x16x32_bf16(a, b, c, 0, 0, 0);
}

// ---------------- prep: x -> bf16, zero counts ----------------
__global__ void k_prep(const float* __restrict__ x, bf16_t* __restrict__ xbf,
                       int* __restrict__ counts) {
  if (blockIdx.x == 0 && threadIdx.x < E_NUM) counts[threadIdx.x] = 0;
  int idx = blockIdx.x * 256 + threadIdx.x;
  const int total = T_TOK * H_DIM / 8;
  if (idx < total) {
    f32x4 a = ((const f32x4*)x)[2 * idx];
    f32x4 b = ((const f32x4*)x)[2 * idx + 1];
    bf16x8 o = {(bf16_t)a[0], (bf16_t)a[1], (bf16_t)a[2], (bf16_t)a[3],
                (bf16_t)b[0], (bf16_t)b[1], (bf16_t)b[2], (bf16_t)b[3]};
    ((bf16x8*)xbf)[idx] = o;
  }
}

// ---------------- router ----------------
__global__ void k_router(const float* __restrict__ x, const float* __restrict__ gw,
                         const float* __restrict__ gb, float* __restrict__ topw,
                         int* __restrict__ counts, int* __restrict__ rowsl) {
  const int t = blockIdx.x;
  const int lane = threadIdx.x;      // 64 threads
  const int c = lane >> 4, e = lane & 15;
  const f32x4* x4 = (const f32x4*)(x + (size_t)t * H_DIM);
  const f32x4* w4 = (const f32x4*)(gw + (size_t)e * H_DIM);
  float p = 0.f;
  const int per = (H_DIM / 4) / 4;
  for (int i = c * per; i < (c + 1) * per; ++i) {
    f32x4 xv = x4[i], wv = w4[i];
    p += xv[0] * wv[0] + xv[1] * wv[1] + xv[2] * wv[2] + xv[3] * wv[3];
  }
  p += __shfl_xor(p, 16);
  p += __shfl_xor(p, 32);
  p += gb[e];
  __shared__ float lg[E_NUM];
  if (lane < E_NUM) lg[lane] = p;
  __syncthreads();
  if (lane == 0) {
    float v[E_NUM];
    #pragma unroll
    for (int i = 0; i < E_NUM; ++i) v[i] = lg[i];
    int idxs[TOPK]; float vals[TOPK];
    for (int k = 0; k < TOPK; ++k) {
      int bi = 0; float bv = -1e30f;
      for (int i = 0; i < E_NUM; ++i) {
        if (v[i] > bv) { bv = v[i]; bi = i; }
      }
      idxs[k] = bi; vals[k] = bv; v[bi] = -1e30f;
    }
    float m = vals[0], s = 0.f, w[TOPK];
    for (int k = 0; k < TOPK; ++k) { w[k] = expf(vals[k] - m); s += w[k]; }
    for (int k = 0; k < TOPK; ++k) {
      int slot = t * TOPK + k;
      topw[slot] = w[k] / s;
      int pos = atomicAdd(&counts[idxs[k]], 1);
      rowsl[idxs[k] * T_TOK + pos] = slot;
    }
  }
}

// ============== GEMM1: h = x @ wgu^T (+bias), swiglu -> act (bf16) =========
// Counted-vmcnt pipeline: tokens dist-1 via global_load_lds (dbuf LDS),
// fp32 weights dist-3 via alternating reg sets (wA/wB), raw s_barrier.
// Per-iter VMEM FIFO: [W_{k+1}(8) | T_k(4) | W_{k+2}(8) | T_{k+1}(4)] -> vmcnt(12).

#define G1_STAGE_T(KT, BUF) do {                                        \
    int c1_ = (KT) > (NK - 1) ? (NK - 1) : (KT);                        \
    _Pragma("unroll")                                                   \
    for (int i_ = 0; i_ < 4; ++i_)                                      \
      gload16(tsrc[i_] + c1_ * BK, &sT[BUF][w * 2048 + i_ * 512]);      \
  } while (0)

#define G1_MFMA(CUR) do {                                               \
    _Pragma("unroll")                                                   \
    for (int ks = 0; ks < 2; ++ks) {                                    \
      const int koff = ks * 32 + (lane >> 4) * 8;                       \
      bf16x8 wg_[2], wl_[2], tf[4];                                     \
      _Pragma("unroll")                                                 \
      for (int wi = 0; wi < 2; ++wi) {                                  \
        int rg = 32 * wm + 16 * wi + (lane & 15);                       \
        int swz = koff ^ ((rg & 7) << 3);                               \
        wg_[wi] = *(const bf16x8*)(&sW[CUR][rg * 64 + swz]);            \
        wl_[wi] = *(const bf16x8*)(&sW[CUR][(rg + 64) * 64 + swz]);     \
      }                                                                 \
      _Pragma("unroll")                                                 \
      for (int tj = 0; tj < 4; ++tj) {                                  \
        int rt = 64 * wt + 16 * tj + (lane & 15);                       \
        tf[tj] = *(const bf16x8*)(&sT[CUR][rt * 64 + (koff ^ ((rt & 7) << 3))]); \
      }                                                                 \
      _Pragma("unroll")                                                 \
      for (int wi = 0; wi < 2; ++wi)                                    \
        _Pragma("unroll")                                               \
        for (int tj = 0; tj < 4; ++tj) {                                \
          accg[wi][tj] = mfma16(wg_[wi], tf[tj], accg[wi][tj]);         \
          accl[wi][tj] = mfma16(wl_[wi], tf[tj], accl[wi][tj]);         \
        }                                                               \
    }                                                                   \
  } while (0)

#define G1_ITER(KK, WSET) do {                                          \
    const int cur_ = (KK) & 1;                                          \
    G1_STAGE_T((KK) + 1, cur_ ^ 1);                                     \
    WAITV(12);                                                          \
    _Pragma("unroll")                                                   \
    for (int p_ = 0; p_ < 8; ++p_) {                                    \
      bf16x4 b_ = {(bf16_t)WSET[p_][0], (bf16_t)WSET[p_][1],            \
                   (bf16_t)WSET[p_][2], (bf16_t)WSET[p_][3]};           \
      *(bf16x4*)(&sW[cur_ ^ 1][wo[p_]]) = b_;                           \
    }                                                                   \
    { int c3_ = (KK) + 3 > (NK - 1) ? (NK - 1) : (KK) + 3;              \
      _Pragma("unroll")                                                 \
      for (int p_ = 0; p_ < 8; ++p_)                                    \
        WSET[p_] = *(const f32x4*)(wbase + wgo[p_] + c3_ * BK); }       \
    WAITL(); BAR();                                                     \
    G1_MFMA(cur_);                                                      \
    WAITL(); BAR();                                                     \
  } while (0)

__global__ __launch_bounds__(256, 2)
void k_gemm1(const bf16_t* __restrict__ xbf, const float* __restrict__ wgu,
             const float* __restrict__ bgu, const float* __restrict__ al,
             const float* __restrict__ be, const float* __restrict__ lim_,
             const int* __restrict__ counts, const int* __restrict__ rowsl,
             bf16_t* __restrict__ act) {
  const int nwg = E_NUM * NT1 * MT_MAX;
  const int L = (blockIdx.x & 7) * (nwg >> 3) + (blockIdx.x >> 3);
  const int mt = L & (MT_MAX - 1);
  const int t2 = L >> 4;
  const int nt = t2 % NT1;
  const int e  = t2 / NT1;
  const int Ne = counts[e];
  const int m0 = mt * BT;
  if (m0 >= Ne) return;
  const int n0 = nt * 64;

  __shared__ alignas(16) bf16_t sW[2][128 * 64];  // rows 0-63 gate, 64-127 lin
  __shared__ alignas(16) bf16_t sT[2][128 * 64];

  const int tid = threadIdx.x;
  const int w = tid >> 6, lane = tid & 63;
  const int wm = w & 1, wt = w >> 1;
  const int* rl = rowsl + e * T_TOK;

  const bf16_t* tsrc[4];
  {
    const int r_ = lane >> 3, cc = lane & 7;
    #pragma unroll
    for (int i = 0; i < 4; ++i) {
      int r = w * 32 + i * 8 + r_;
      int li = m0 + r; if (li > Ne - 1) li = Ne - 1;
      int tok = rl[li] >> 2;
      tsrc[i] = xbf + (size_t)tok * H_DIM + ((cc ^ (r & 7)) << 3);
    }
  }

  const int wrow = tid >> 4, wf = tid & 15;
  const float* wbase = wgu + (size_t)e * (2 * I_DIM) * H_DIM + wf * 4;
  int wgo[8], wo[8];
  #pragma unroll
  for (int p = 0; p < 8; ++p) {
    int row = wrow + p * 16;   // 0..127
    int grow = (row < 64) ? (n0 + row) : (I_DIM + n0 + row - 64);
    wgo[p] = grow * H_DIM;
    wo[p] = row * 64 + ((wf * 4) ^ ((row & 7) << 3));
  }

  f32x4 zero = {0.f, 0.f, 0.f, 0.f};
  f32x4 accg[2][4], accl[2][4];
  #pragma unroll
  for (int i = 0; i < 2; ++i)
    #pragma unroll
    for (int j = 0; j < 4; ++j) { accg[i][j] = zero; accl[i][j] = zero; }

  f32x4 wA[8], wB[8];
  // ---- prologue: T_0 -> sT[0]; W_0 -> wA -> sW[0]; W_1 -> wA; W_2 -> wB
  G1_STAGE_T(0, 0);
  #pragma unroll
  for (int p = 0; p < 8; ++p) wA[p] = *(const f32x4*)(wbase + wgo[p]);
  WAITV(0);
  #pragma unroll
  for (int p = 0; p < 8; ++p) {
    bf16x4 b = {(bf16_t)wA[p][0], (bf16_t)wA[p][1],
                (bf16_t)wA[p][2], (bf16_t)wA[p][3]};
    *(bf16x4*)(&sW[0][wo[p]]) = b;
  }
  #pragma unroll
  for (int p = 0; p < 8; ++p) wA[p] = *(const f32x4*)(wbase + wgo[p] + 1 * BK);
  #pragma unroll
  for (int p = 0; p < 8; ++p) wB[p] = *(const f32x4*)(wbase + wgo[p] + 2 * BK);
  WAITL(); BAR();

  // ---- main loop: 45 iters = 22 pairs + 1 (reg-set parity static)
  for (int kb = 0; kb < NK - 1; kb += 2) {
    G1_ITER(kb, wA);
    G1_ITER(kb + 1, wB);
  }
  G1_ITER(NK - 1, wA);

  // ---- epilogue
  const float alpha = al[e], beta = be[e], lim = lim_[e];
  const float* bgp = bgu + (size_t)e * (2 * I_DIM);
  #pragma unroll
  for (int wi = 0; wi < 2; ++wi) {
    const int nb = n0 + 32 * wm + 16 * wi + ((lane >> 4) << 2);
    f32x4 bg4 = *(const f32x4*)(bgp + nb);
    f32x4 bl4 = *(const f32x4*)(bgp + I_DIM + nb);
    #pragma unroll
    for (int tj = 0; tj < 4; ++tj) {
      const int li2 = m0 + 64 * wt + 16 * tj + (lane & 15);
      if (li2 < Ne) {
        const int slot = rl[li2];
        bf16x4 ov;
        #pragma unroll
        for (int r = 0; r < 4; ++r) {
          float g = accg[wi][tj][r] + bg4[r];
          float l = accl[wi][tj][r] + bl4[r];
          g = fminf(g, lim);
          l = fminf(fmaxf(l, -lim), lim);
          float sg = 1.0f / (1.0f + expf(-alpha * g));
          ov[r] = (bf16_t)(g * sg * (l + beta));
        }
        *(bf16x4*)(&act[(size_t)slot * I_DIM + nb]) = ov;
      }
    }
  }
}

// ============== GEMM2: y = act @ wd^T + bd, scaled =========================
// Same pipeline; 64 weight rows -> 4-reg sets, vmcnt(8); 48 KB LDS -> 3 blk/CU.

#define G2_STAGE_T(KT, BUF) do {                                        \
    int c1_ = (KT) > (NK - 1) ? (NK - 1) : (KT);                        \
    _Pragma("unroll")                                                   \
    for (int i_ = 0; i_ < 4; ++i_)                                      \
      gload16(tsrc[i_] + c1_ * BK, &sT[BUF][w * 2048 + i_ * 512]);      \
  } while (0)

#define G2_MFMA(CUR) do {                                               \
    _Pragma("unroll")                                                   \
    for (int ks = 0; ks < 2; ++ks) {                                    \
      const int koff = ks * 32 + (lane >> 4) * 8;                       \
      bf16x8 wf_[2], tf[4];                                             \
      _Pragma("unroll")                                                 \
      for (int wi = 0; wi < 2; ++wi) {                                  \
        int rg = 32 * wm + 16 * wi + (lane & 15);                       \
        wf_[wi] = *(const bf16x8*)(&sW[CUR][rg * 64 + (koff ^ ((rg & 7) << 3))]); \
      }                                                                 \
      _Pragma("unroll")                                                 \
      for (int tj = 0; tj < 4; ++tj) {                                  \
        int rt = 64 * wt + 16 * tj + (lane & 15);                       \
        tf[tj] = *(const bf16x8*)(&sT[CUR][rt * 64 + (koff ^ ((rt & 7) << 3))]); \
      }                                                                 \
      _Pragma("unroll")                                                 \
      for (int wi = 0; wi < 2; ++wi)                                    \
        _Pragma("unroll")                                               \
        for (int tj = 0; tj < 4; ++tj)                                  \
          acc[wi][tj] = mfma16(wf_[wi], tf[tj], acc[wi][tj]);           \
    }                                                                   \
  } while (0)

#define G2_ITER(KK, WSET) do {                                          \
    const int cur_ = (KK) & 1;                                          \
    G2_STAGE_T((KK) + 1, cur_ ^ 1);                                     \
    WAITV(8);                                                           \
    _Pragma("unroll")                                                   \
    for (int p_ = 0; p_ < 4; ++p_) {                                    \
      bf16x4 b_ = {(bf16_t)WSET[p_][0], (bf16_t)WSET[p_][1],            \
                   (bf16_t)WSET[p_][2], (bf16_t)WSET[p_][3]};           \
      *(bf16x4*)(&sW[cur_ ^ 1][wo[p_]]) = b_;                           \
    }                                                                   \
    { int c3_ = (KK) + 3 > (NK - 1) ? (NK - 1) : (KK) + 3;              \
      _Pragma("unroll")                                                 \
      for (int p_ = 0; p_ < 4; ++p_)                                    \
        WSET[p_] = *(const f32x4*)(wbase + wgo[p_] + c3_ * BK); }       \
    WAITL(); BAR();                                                     \
    G2_MFMA(cur_);                                                      \
    WAITL(); BAR();                                                     \
  } while (0)

__global__ __launch_bounds__(256, 3)
void k_gemm2(const bf16_t* __restrict__ act, const float* __restrict__ wd,
             const float* __restrict__ bd, const float* __restrict__ topw,
             const int* __restrict__ counts, const int* __restrict__ rowsl,
             float* __restrict__ ybuf) {
  const int nwg = E_NUM * NT2 * MT_MAX;
  const int L = (blockIdx.x & 7) * (nwg >> 3) + (blockIdx.x >> 3);
  const int mt = L & (MT_MAX - 1);
  const int t2 = L >> 4;
  const int ht = t2 % NT2;
  const int e  = t2 / NT2;
  const int Ne = counts[e];
  const int m0 = mt * BT;
  if (m0 >= Ne) return;
  const int h0 = ht * 64;

  __shared__ alignas(16) bf16_t sW[2][64 * 64];
  __shared__ alignas(16) bf16_t sT[2][128 * 64];

  const int tid = threadIdx.x;
  const int w = tid >> 6, lane = tid & 63;
  const int wm = w & 1, wt = w >> 1;
  const int* rl = rowsl + e * T_TOK;

  const bf16_t* tsrc[4];
  {
    const int r_ = lane >> 3, cc = lane & 7;
    #pragma unroll
    for (int i = 0; i < 4; ++i) {
      int r = w * 32 + i * 8 + r_;
      int li = m0 + r; if (li > Ne - 1) li = Ne - 1;
      int slot = rl[li];
      tsrc[i] = act + (size_t)slot * I_DIM + ((cc ^ (r & 7)) << 3);
    }
  }

  const int wrow = tid >> 4, wf = tid & 15;
  const float* wbase = wd + (size_t)e * H_DIM * I_DIM + wf * 4;
  int wgo[4], wo[4];
  #pragma unroll
  for (int p = 0; p < 4; ++p) {
    int row = wrow + p * 16;   // 0..63
    wgo[p] = (h0 + row) * I_DIM;
    wo[p] = row * 64 + ((wf * 4) ^ ((row & 7) << 3));
  }

  f32x4 zero = {0.f, 0.f, 0.f, 0.f};
  f32x4 acc[2][4];
  #pragma unroll
  for (int i = 0; i < 2; ++i)
    #pragma unroll
    for (int j = 0; j < 4; ++j) acc[i][j] = zero;

  f32x4 wA[4], wB[4];
  G2_STAGE_T(0, 0);
  #pragma unroll
  for (int p = 0; p < 4; ++p) wA[p] = *(const f32x4*)(wbase + wgo[p]);
  WAITV(0);
  #pragma unroll
  for (int p = 0; p < 4; ++p) {
    bf16x4 b = {(bf16_t)wA[p][0], (bf16_t)wA[p][1],
                (bf16_t)wA[p][2], (bf16_t)wA[p][3]};
    *(bf16x4*)(&sW[0][wo[p]]) = b;
  }
  #pragma unroll
  for (int p = 0; p < 4; ++p) wA[p] = *(const f32x4*)(wbase + wgo[p] + 1 * BK);
  #pragma unroll
  for (int p = 0; p < 4; ++p) wB[p] = *(const f32x4*)(wbase + wgo[p] + 2 * BK);
  WAITL(); BAR();

  for (int kb = 0; kb < NK - 1; kb += 2) {
    G2_ITER(kb, wA);
    G2_ITER(kb + 1, wB);
  }
  G2_ITER(NK - 1, wA);

  const float* bdp = bd + (size_t)e * H_DIM;
  #pragma unroll
  for (int wi = 0; wi < 2; ++wi) {
    const int hb = h0 + 32 * wm + 16 * wi + ((lane >> 4) << 2);
    f32x4 b4 = *(const f32x4*)(bdp + hb);
    #pragma unroll
    for (int tj = 0; tj < 4; ++tj) {
      const int li2 = m0 + 64 * wt + 16 * tj + (lane & 15);
      if (li2 < Ne) {
        const int slot = rl[li2];
        const float tw = topw[slot];
        f32x4 o = (acc[wi][tj] + b4) * tw;
        *(f32x4*)(&ybuf[(size_t)slot * H_DIM + hb]) = o;
      }
    }
  }
}

// ---------------- combine ----------------------
__global__ void k_combine(const float* __restrict__ ybuf, float* __restrict__ out) {
  const int j4 = H_DIM / 4;
  int idx = blockIdx.x * 256 + threadIdx.x;
  if (idx >= T_TOK * j4) return;
  int t = idx / j4, j = idx - t * j4;
  const f32x4* yb = (const f32x4*)ybuf;
  f32x4 s = yb[(size_t)(t * 4 + 0) * j4 + j];
  s = s + yb[(size_t)(t * 4 + 1) * j4 + j];
  s = s + yb[(size_t)(t * 4 + 2) * j4 + j];
  s = s + yb[(size_t)(t * 4 + 3) * j4 + j];
  ((f32x4*)out)[idx] = s;
}

// ---------------- host launcher ----------------
extern "C" void kernel_launch(void* const* d_in, const int* in_sizes, int n_in,
                              void* d_out, int out_size, void* d_ws, size_t ws_size,
                              hipStream_t stream) {
  const float* x   = (const float*)d_in[0];
  const float* gw  = (const float*)d_in[1];
  const float* gb  = (const float*)d_in[2];
  const float* wgu = (const float*)d_in[3];
  const float* bgu = (const float*)d_in[4];
  const float* wd  = (const float*)d_in[5];
  const float* bd  = (const float*)d_in[6];
  const float* sal = (const float*)d_in[7];
  const float* sbe = (const float*)d_in[8];
  const float* sli = (const float*)d_in[9];
  float* out = (float*)d_out;

  char* ws = (char*)d_ws;
  int*    counts = (int*)(ws + 0);
  int*    rowsl  = (int*)(ws + 4096);
  float*  topw   = (float*)(ws + 4096 + 131072);
  bf16_t* xbf    = (bf16_t*)(ws + (1 << 20));
  bf16_t* act    = (bf16_t*)(ws + (size_t)(16 << 20));
  float*  ybuf   = (float*)(ws + (size_t)(64 << 20));

  k_prep<<<dim3(2880), dim3(256), 0, stream>>>(x, xbf, counts);
  k_router<<<dim3(T_TOK), dim3(64), 0, stream>>>(x, gw, gb, topw, counts, rowsl);
  k_gemm1<<<dim3(E_NUM * NT1 * MT_MAX), dim3(256), 0, stream>>>(
      xbf, wgu, bgu, sal, sbe, sli, counts, rowsl, act);
  k_gemm2<<<dim3(E_NUM * NT2 * MT_MAX), dim3(256), 0, stream>>>(
      act, wd, bd, topw, counts, rowsl, ybuf);
  k_combine<<<dim3(5760), dim3(256), 0, stream>>>(ybuf, out);
}